// Round 11
// baseline (186.120 us; speedup 1.0000x reference)
//
#include <hip/hip_runtime.h>
#include <stdint.h>

// out = conv3x3_zeropad(s, W_eff), s = 3x3 reflect-pad box sum of x (B=16,C=64,H=W=128)
// R16 == R15 resubmit (container infra failure; kernel statically re-audited:
// uniform barriers, bounds OK, bijective swizzle, ~112 VGPR < 128 cap).
// R14 (verified, 48.9us) + intra-block 2-strip pipeline: grid 512, each
// block does strips h0 and h0+2; strip-B's 12 initial x-loads issue right
// after strip-A's staging barrier (pinned by sched_barrier(0)), draining
// under strip-A's taploop+epilogue -> one staging-latency exposure per 2
// strips, half the grid rounds. Staging body / double-XOR swizzle / pipelined
// taploop / epilogue are the verified R14 code, parameterized by h0.

#define THETA 0.7f

typedef __attribute__((ext_vector_type(8))) short bf16x8;
typedef __attribute__((ext_vector_type(16))) float f32x16;

__device__ inline unsigned short f2bf(float f) {
    unsigned u = __float_as_uint(f);
    u = (u + 0x7FFFu + ((u >> 16) & 1u)) >> 16;   // RNE
    return (unsigned short)u;
}
__device__ inline unsigned cvt_pk_bf16(float lo, float hi) {
    unsigned r;
    asm volatile("v_cvt_pk_bf16_f32 %0, %1, %2" : "=v"(r) : "v"(lo), "v"(hi));
    return r;   // lo16 = bf16(lo), hi16 = bf16(hi), RNE
}

// ---------------------------------------------------------------------------
// Kernel 1: W_eff -> Wt2 bf16, lane-contiguous MFMA-A layout (verified):
// Wt2[(((tap*4+ic)*2+mf)*64 + lane)*8 + j] = W_eff[o][ch][tap]
//   o = mf*32 + (lane&31), ch = ic*16 + (lane>>5)*8 + j
// ---------------------------------------------------------------------------
__global__ void weff_kernel(const float* __restrict__ W, unsigned short* __restrict__ Wt2) {
    int t = blockIdx.x * blockDim.x + threadIdx.x;   // 512 threads
    if (t >= 512) return;
    int o = t >> 3;
    int ch8 = t & 7;
    int c0 = ch8 * 8;
    int ic = ch8 >> 1;
    int mf = o >> 5;
    int lane = (o & 31) | ((ch8 & 1) << 5);

    float v[8][9];
    float tsum[8];
#pragma unroll
    for (int j = 0; j < 8; j++) {
        const float* w = W + ((size_t)o * 64 + c0 + j) * 9;
        float sum = 0.f;
#pragma unroll
        for (int k = 0; k < 9; k++) { v[j][k] = w[k]; sum += v[j][k]; }
        tsum[j] = sum;
    }
#pragma unroll
    for (int tap = 0; tap < 9; tap++) {
        unsigned short* dst = Wt2 + (((size_t)(tap * 4 + ic) * 2 + mf) * 64 + lane) * 8;
#pragma unroll
        for (int j = 0; j < 8; j++) {
            float val = v[j][tap] - ((tap == 4) ? THETA * tsum[j] : 0.f);
            dst[j] = f2bf(val);
        }
    }
}

// ---------------------------------------------------------------------------
// Staging body (verified R14): rolling vertical sums from preloaded A/Bv/C,
// shfl horizontal with reflect, cvt_pk pack, double-XOR swizzled 8B writes.
// Thread = (w4 = tid&31, cg = tid>>5 -> 4 ch).
// ---------------------------------------------------------------------------
__device__ __forceinline__ void stage_rows(unsigned short* __restrict__ sS,
                                           const float* __restrict__ xp,
                                           int h0, int w4, int u8, int hh,
                                           float4 A[4], float4 Bv[4], float4 C[4]) {
#pragma unroll
    for (int rr = 0; rr < 4; rr++) {
        int hg = h0 - 1 + rr;
        if (hg < 0 || hg > 127) continue;     // block-uniform skip (pre-zeroed)

        float4 Cn[4];
        if (rr < 3) {
            int hn = hg + 2;
            if (hn > 127) hn = 126;           // vertical reflect down
#pragma unroll
            for (int cc = 0; cc < 4; cc++)
                Cn[cc] = *(const float4*)(xp + (size_t)cc * 16384 + (size_t)hn * 128);
        }

        float rf[4][4];   // [cc][k]
#pragma unroll
        for (int cc = 0; cc < 4; cc++) {
            float4 vs;
            vs.x = A[cc].x + Bv[cc].x + C[cc].x;
            vs.y = A[cc].y + Bv[cc].y + C[cc].y;
            vs.z = A[cc].z + Bv[cc].z + C[cc].z;
            vs.w = A[cc].w + Bv[cc].w + C[cc].w;
            float L = __shfl_up(vs.w, 1, 32);
            float R = __shfl_down(vs.x, 1, 32);
            rf[cc][0] = (w4 == 0) ? vs.x + 2.f * vs.y : L + vs.x + vs.y;
            rf[cc][1] = vs.x + vs.y + vs.z;
            rf[cc][2] = vs.y + vs.z + vs.w;
            rf[cc][3] = (w4 == 31) ? 2.f * vs.z + vs.w : vs.z + vs.w + R;
        }
#pragma unroll
        for (int k = 0; k < 4; k++) {
            int slot = w4 * 4 + k + 1;        // w = w4*4+k -> slot w+1
            uint2 o2 = make_uint2(cvt_pk_bf16(rf[0][k], rf[1][k]),
                                  cvt_pk_bf16(rf[2][k], rf[3][k]));
            int p = u8 ^ (slot & 7) ^ ((slot >> 2) & 7);
            *(uint2*)(sS + (size_t)(rr * 132 + slot) * 64 + (p << 3) + hh) = o2;
        }
        if (rr < 3) {
#pragma unroll
            for (int cc = 0; cc < 4; cc++) { A[cc] = Bv[cc]; Bv[cc] = C[cc]; C[cc] = Cn[cc]; }
        }
    }
}

// ---------------------------------------------------------------------------
// Conv strip (verified R14): software-pipelined 9-tap MFMA loop + epilogue.
// ---------------------------------------------------------------------------
__device__ __forceinline__ void conv_strip(const unsigned short* __restrict__ sS,
                                           const unsigned short* __restrict__ Wt2,
                                           float* __restrict__ out,
                                           int b, int h0, int lane, int orow,
                                           int ohalf, int whalf, int n32, int q2,
                                           const int (*p0)[4]) {
    f32x16 acc[2];
#pragma unroll
    for (int nf = 0; nf < 2; nf++)
#pragma unroll
        for (int r = 0; r < 16; r++) acc[nf][r] = 0.f;

    bf16x8 Af[4], An[4], B0[4], B0n[4], B1[4];
#pragma unroll
    for (int ic = 0; ic < 4; ic++) {
        Af[ic] = *(const bf16x8*)(Wt2 + (((size_t)(0 * 4 + ic) * 2 + ohalf) * 64 + lane) * 8);
        B0[ic] = *(const bf16x8*)(sS + (size_t)(orow + 0) * 8448 + p0[0][ic]);
    }

#pragma unroll
    for (int tap = 0; tap < 9; tap++) {
        int ky = tap / 3, kx = tap % 3;
        const unsigned short* brow = sS + (size_t)(orow + ky) * 8448;
#pragma unroll
        for (int ic = 0; ic < 4; ic++)
            B1[ic] = *(const bf16x8*)(brow + p0[kx][ic] + 2048);
        if (tap < 8) {
            int kyn = (tap + 1) / 3, kxn = (tap + 1) % 3;
            const unsigned short* brn = sS + (size_t)(orow + kyn) * 8448;
#pragma unroll
            for (int ic = 0; ic < 4; ic++) {
                B0n[ic] = *(const bf16x8*)(brn + p0[kxn][ic]);
                An[ic] = *(const bf16x8*)(Wt2 + (((size_t)((tap + 1) * 4 + ic) * 2 + ohalf) * 64 + lane) * 8);
            }
        }
#pragma unroll
        for (int ic = 0; ic < 4; ic++)
            acc[0] = __builtin_amdgcn_mfma_f32_32x32x16_bf16(Af[ic], B0[ic], acc[0], 0, 0, 0);
#pragma unroll
        for (int ic = 0; ic < 4; ic++)
            acc[1] = __builtin_amdgcn_mfma_f32_32x32x16_bf16(Af[ic], B1[ic], acc[1], 0, 0, 0);
        if (tap < 8) {
#pragma unroll
            for (int k = 0; k < 4; k++) { Af[k] = An[k]; B0[k] = B0n[k]; }
        }
    }

    // epilogue: 32x32 C/D layout col=lane&31 (pixel), row=(r&3)+8*(r>>2)+4*q2 (o)
    float* ob = out + ((size_t)b * 64) * 16384 + (size_t)(h0 + orow) * 128 + whalf * 64;
#pragma unroll
    for (int nf = 0; nf < 2; nf++)
#pragma unroll
        for (int r = 0; r < 16; r++) {
            int o = ohalf * 32 + (r & 3) + 8 * (r >> 2) + 4 * q2;
            ob[(size_t)o * 16384 + nf * 32 + n32] = acc[nf][r];
        }
}

// ---------------------------------------------------------------------------
// Kernel 2: fused boxsum + implicit-GEMM conv, 2 strips per block.
// Block = (b, strips h0=base and base+2, full 128 px), 512 thr / 8 waves;
// wave = (ohalf, orow, whalf): 1 row x 64 px x 32 o, acc[2], 72 MFMA/strip.
// LDS s-tile: [4 rows][132 slots][64 c] bf16 = 67584 B -> 2 blocks/CU.
// Grid 512 = 16 b x 32 double-strips, XCD-swizzled (512%8==0, bijective).
// ---------------------------------------------------------------------------
__global__ __launch_bounds__(512, 4) void fused_kernel(const float* __restrict__ x,
                                                       const unsigned short* __restrict__ Wt2,
                                                       float* __restrict__ out) {
    __shared__ __align__(16) unsigned short sS[4 * 132 * 64];   // 67584 B

    int bid0 = blockIdx.x;
    int bid = (bid0 & 7) * 64 + (bid0 >> 3);   // 8 XCDs x 64 contiguous blocks
    int b = bid >> 5;
    int base = (bid & 31) * 4;                 // strip A h0 = base (0..124)
    int tid = threadIdx.x;
    int lane = tid & 63;
    int wv = tid >> 6;
    int n32 = lane & 31;
    int q2 = lane >> 5;
    int ohalf = wv >> 2;
    int orow = (wv >> 1) & 1;
    int whalf = wv & 1;

    int w4 = tid & 31;
    int cg = tid >> 5;
    int u8 = cg >> 1;
    int hh = (cg & 1) * 4;
    const float* xp = x + ((size_t)(b * 64 + cg * 4)) * 16384 + w4 * 4;

    // zero-pad slots 0 (w=-1) and 129 (w=128), rows 0..3 (persist: staging
    // writes only slots 1..128, both strips)
    int4 z = make_int4(0, 0, 0, 0);
    if (tid < 64) {
        int rr = tid >> 4;
        int sl = ((tid >> 3) & 1) ? 129 : 0;
        int g = tid & 7;
        *(int4*)((char*)sS + ((size_t)(rr * 132 + sl) * 8 + g) * 16) = z;
    }

    // ---- strip A: h0 = base ----
    int h0 = base;
    if (h0 == 0)   // zero s-row 0 (hg = -1)
        for (int i = tid; i < 1056; i += 512) *(int4*)((char*)sS + (size_t)i * 16) = z;
    {
        int hgf = (h0 == 0) ? 0 : h0 - 1;
        int hm = (hgf == 0) ? 1 : hgf - 1;
        float4 A[4], Bv[4], C[4];
#pragma unroll
        for (int cc = 0; cc < 4; cc++) {
            A[cc]  = *(const float4*)(xp + (size_t)cc * 16384 + (size_t)hm * 128);
            Bv[cc] = *(const float4*)(xp + (size_t)cc * 16384 + (size_t)hgf * 128);
            C[cc]  = *(const float4*)(xp + (size_t)cc * 16384 + (size_t)(hgf + 1) * 128);
        }
        stage_rows(sS, xp, h0, w4, u8, hh, A, Bv, C);
    }
    __syncthreads();

    // ---- preload strip B initial rows (h0b = base+2 >= 2: no edge cases) ----
    // Issued here, pinned, consumed after strip A's taploop+epilogue.
    int h0b = base + 2;
    float4 PA[4], PB[4], PC[4];
#pragma unroll
    for (int cc = 0; cc < 4; cc++) {
        PA[cc] = *(const float4*)(xp + (size_t)cc * 16384 + (size_t)(h0b - 2) * 128);
        PB[cc] = *(const float4*)(xp + (size_t)cc * 16384 + (size_t)(h0b - 1) * 128);
        PC[cc] = *(const float4*)(xp + (size_t)cc * 16384 + (size_t)h0b * 128);
    }
    __builtin_amdgcn_sched_barrier(0);   // do not sink the preloads

    // B LDS offsets (shorts) per (kx, ic), shared by both strips
    int p0[3][4];
#pragma unroll
    for (int kx = 0; kx < 3; kx++)
#pragma unroll
        for (int ic = 0; ic < 4; ic++) {
            int slot = n32 + kx + whalf * 64;
            int g = (ic * 2 + q2) ^ (slot & 7) ^ ((slot >> 2) & 7);
            p0[kx][ic] = slot * 64 + g * 8;
        }

    conv_strip(sS, Wt2, out, b, h0, lane, orow, ohalf, whalf, n32, q2, p0);
    __syncthreads();   // strip A ds_reads done before strip B overwrites sS

    // ---- strip B: h0b = base + 2 (can be 126, never 0) ----
    if (h0b == 126)   // zero s-row 3 (hg = 128)
        for (int i = tid; i < 1056; i += 512) *(int4*)((char*)sS + (size_t)(3168 + i) * 16) = z;
    stage_rows(sS, xp, h0b, w4, u8, hh, PA, PB, PC);
    __syncthreads();

    conv_strip(sS, Wt2, out, b, h0b, lane, orow, ohalf, whalf, n32, q2, p0);
}

// ---------------------------------------------------------------------------
extern "C" void kernel_launch(void* const* d_in, const int* in_sizes, int n_in,
                              void* d_out, int out_size, void* d_ws, size_t ws_size,
                              hipStream_t stream) {
    const float* x = (const float*)d_in[0];   // [16][64][128][128] fp32
    const float* W = (const float*)d_in[1];   // [64][64][3][3] fp32
    float* outp = (float*)d_out;

    // ws: Wt2 bf16 (73728 B); no global s intermediate
    unsigned short* Wt2 = (unsigned short*)d_ws;

    weff_kernel<<<2, 256, 0, stream>>>(W, Wt2);
    fused_kernel<<<512, 512, 0, stream>>>(x, Wt2, outp);
}